// Round 4
// baseline (521.755 us; speedup 1.0000x reference)
//
#include <hip/hip_runtime.h>
#include <hip/hip_bf16.h>

#define N_TOK 131072
#define DIM   512
#define HID   512
#define NEXP  10

using bf16x8 = __attribute__((ext_vector_type(8))) short;
using f32x4  = __attribute__((ext_vector_type(4))) float;

__device__ __forceinline__ short f2bf(float f) {
    union { float f; unsigned u; } v; v.f = f;
    unsigned u = v.u;
    return (short)((u + 0x7FFFu + ((u >> 16) & 1u)) >> 16);   // RNE
}

// swizzle of the 16B k-slot within a row: spreads 8 rows over 8 bank-groups
#define SWZ(r) (((r) ^ ((r) >> 2)) & 3)

#define GLOAD16(g, l) __builtin_amdgcn_global_load_lds( \
    (const __attribute__((address_space(1))) void*)(g),  \
    (__attribute__((address_space(3))) void*)(l), 16, 0, 0)

// ---------------- router: logits = x @ Wr^T + br, argmax ----------------
__global__ __launch_bounds__(256) void router_kernel(
    const float* __restrict__ x, const float* __restrict__ Wr,
    const float* __restrict__ br, int* __restrict__ eid,
    float* __restrict__ ids_out, int* __restrict__ counts)
{
    __shared__ float wr[NEXP][DIM];
    __shared__ int lcnt[NEXP];
    int tid = threadIdx.x;
    for (int i = tid; i < NEXP * DIM / 4; i += 256)
        ((float4*)wr)[i] = ((const float4*)Wr)[i];
    if (tid < NEXP) lcnt[tid] = 0;
    __syncthreads();

    int lane  = tid & 63;
    int wave  = tid >> 6;
    int gwave = blockIdx.x * 4 + wave;
    int nwav  = gridDim.x * 4;

    for (int t = gwave; t < N_TOK; t += nwav) {
        const float4* xr = (const float4*)(x + (size_t)t * DIM);
        float4 v0 = xr[lane * 2], v1 = xr[lane * 2 + 1];
        float xf[8] = {v0.x, v0.y, v0.z, v0.w, v1.x, v1.y, v1.z, v1.w};
        float dot[NEXP];
        #pragma unroll
        for (int e = 0; e < NEXP; ++e) {
            const float* wv = &wr[e][lane * 8];
            float s = 0.f;
            #pragma unroll
            for (int j = 0; j < 8; ++j) s = fmaf(xf[j], wv[j], s);
            dot[e] = s;
        }
        #pragma unroll
        for (int off = 32; off > 0; off >>= 1) {
            #pragma unroll
            for (int e = 0; e < NEXP; ++e) dot[e] += __shfl_xor(dot[e], off, 64);
        }
        if (lane == 0) {
            int best = 0; float bv = dot[0] + br[0];
            #pragma unroll
            for (int e = 1; e < NEXP; ++e) {
                float v = dot[e] + br[e];
                if (v > bv) { bv = v; best = e; }
            }
            eid[t] = best;
            ids_out[t] = (float)best;
            atomicAdd(&lcnt[best], 1);
        }
    }
    __syncthreads();
    if (tid < NEXP) atomicAdd(&counts[tid], lcnt[tid]);
}

// ---------------- prefix sums: token offsets + tile offsets (128-row tiles) ----------------
__global__ void offsets_kernel(const int* __restrict__ counts,
                               int* __restrict__ offsets, int* __restrict__ toff)
{
    if (threadIdx.x == 0) {
        int acc = 0, ta = 0;
        for (int e = 0; e < NEXP; ++e) {
            offsets[e] = acc; toff[e] = ta;
            acc += counts[e]; ta += (counts[e] + 127) >> 7;
        }
        offsets[NEXP] = acc; toff[NEXP] = ta;
    }
}

// ---------------- bucket scatter: perm[offset[e] + pos] = token ----------------
__global__ __launch_bounds__(256) void scatter_kernel(
    const int* __restrict__ eid, const int* __restrict__ offsets,
    int* __restrict__ cursors, int* __restrict__ perm)
{
    __shared__ int lcnt[NEXP], lbase[NEXP];
    int tid = threadIdx.x;
    if (tid < NEXP) lcnt[tid] = 0;
    __syncthreads();
    int t = blockIdx.x * 256 + tid;
    int e = 0, lpos = 0;
    if (t < N_TOK) {
        e = eid[t];
        lpos = atomicAdd(&lcnt[e], 1);
    }
    __syncthreads();
    if (tid < NEXP) lbase[tid] = atomicAdd(&cursors[tid], lcnt[tid]);
    __syncthreads();
    if (t < N_TOK) perm[offsets[e] + lbase[e] + lpos] = t;
}

// ---------------- transpose-convert weights: [512][512] f32 -> [n][k] bf16 ----------------
__global__ __launch_bounds__(256) void wconvert_kernel(
    const float* __restrict__ W1, const float* __restrict__ W2,
    short* __restrict__ W1bT, short* __restrict__ W2bT)
{
    int mat = blockIdx.z;
    const float* src = (mat < NEXP) ? W1 + (size_t)mat * 512 * 512
                                    : W2 + (size_t)(mat - NEXP) * 512 * 512;
    short* dst = (mat < NEXP) ? W1bT + (size_t)mat * 512 * 512
                              : W2bT + (size_t)(mat - NEXP) * 512 * 512;
    __shared__ float tile[64][65];
    int r0 = blockIdx.y * 64, c0 = blockIdx.x * 64;
    int tid = threadIdx.x;
    int tr = tid >> 4, tc4 = (tid & 15) * 4;
    #pragma unroll
    for (int i = 0; i < 4; ++i) {
        float4 v = *(const float4*)(src + (size_t)(r0 + i * 16 + tr) * 512 + c0 + tc4);
        tile[i * 16 + tr][tc4 + 0] = v.x; tile[i * 16 + tr][tc4 + 1] = v.y;
        tile[i * 16 + tr][tc4 + 2] = v.z; tile[i * 16 + tr][tc4 + 3] = v.w;
    }
    __syncthreads();
    #pragma unroll
    for (int i = 0; i < 4; ++i) {
        int cc = i * 16 + tr;           // output row (= source col)
        ushort4 o;
        o.x = (ushort)f2bf(tile[tc4 + 0][cc]); o.y = (ushort)f2bf(tile[tc4 + 1][cc]);
        o.z = (ushort)f2bf(tile[tc4 + 2][cc]); o.w = (ushort)f2bf(tile[tc4 + 3][cc]);
        *(ushort4*)(dst + (size_t)(c0 + cc) * 512 + r0 + tc4) = o;
    }
}

// ---------------- MFMA expert GEMM: 128 x 256 tile, K=512, 8 waves ----------------
// 3-buffer pipeline, counted vmcnt, raw s_barrier, swizzled LDS k-slots.
// LAYER==1: A = gathered x rows (fp32 regs -> bf16 ds_write), out = relu(.+b1) -> h (bf16)
// LAYER==2: A = packed h rows (per-lane global_load_lds), out = . + b2 -> out[tok] (f32)
template<int LAYER>
__global__ __launch_bounds__(512, 4) void expert_gemm(
    const float* __restrict__ x, const short* __restrict__ hA,
    const short* __restrict__ WT, const float* __restrict__ bias,
    const int* __restrict__ offsets, const int* __restrict__ toff,
    const int* __restrict__ perm,
    short* __restrict__ hOut, float* __restrict__ out)
{
    int g = blockIdx.x;
    if (g >= toff[NEXP]) return;
    int e = 0;
    #pragma unroll
    for (int k = 1; k < NEXP; ++k) e += (g >= toff[k]);
    int beg = offsets[e], cnt = offsets[e + 1] - beg;
    int m0 = (g - toff[e]) * 128;
    int nb = blockIdx.y * 256;

    __shared__ int toks[128];
    __shared__ short Ab[3][128 * 32];   // 8 KB each, [row][k] swizzled 16B slots
    __shared__ short Bb[3][256 * 32];   // 16 KB each

    int tid = threadIdx.x, lane = tid & 63, w = tid >> 6;
    if (tid < 128) toks[tid] = perm[beg + min(m0 + tid, cnt - 1)];
    __syncthreads();

    // ---- staging addresses (source pre-swizzled; LDS dest linear) ----
    const short* WTe = WT + (size_t)e * 512 * 512;
    int srow  = w * 16 + (lane >> 2);     // 0..127 (A row / B row0)
    int kqp   = lane & 3;                  // physical 16B slot
    int brow1 = 128 + srow;
    const short* bSrc0 = WTe + (size_t)(nb + srow) * 512 + (kqp ^ SWZ(srow)) * 8;
    const short* bSrc1 = WTe + (size_t)(nb + brow1) * 512 + (kqp ^ SWZ(brow1)) * 8;

    const float* aSrcF = nullptr;
    const short* aSrcH = nullptr;
    int awrow = tid >> 2;                  // ds_write A row for LAYER 1 (0..127)
    if (LAYER == 1)
        aSrcF = x + (size_t)toks[awrow] * DIM + ((tid & 3) ^ SWZ(awrow)) * 8;
    else
        aSrcH = hA + (size_t)(beg + min(m0 + srow, cnt - 1)) * HID + (kqp ^ SWZ(srow)) * 8;

    auto stageB = [&](int t, int b) {
        GLOAD16(bSrc0 + t * 32, (char*)&Bb[b][0] + w * 1024);
        GLOAD16(bSrc1 + t * 32, (char*)&Bb[b][0] + 8192 + w * 1024);
    };
    auto stageA2 = [&](int t, int b) {
        GLOAD16(aSrcH + t * 32, (char*)&Ab[b][0] + w * 1024);
    };

    float4 aR[2][2];
    auto loadA1 = [&](int t, int s) {
        aR[s][0] = *(const float4*)(aSrcF + t * 32);
        aR[s][1] = *(const float4*)(aSrcF + t * 32 + 4);
    };
    auto writeA1 = [&](int s, int b) {
        bf16x8 p;
        p[0] = f2bf(aR[s][0].x); p[1] = f2bf(aR[s][0].y);
        p[2] = f2bf(aR[s][0].z); p[3] = f2bf(aR[s][0].w);
        p[4] = f2bf(aR[s][1].x); p[5] = f2bf(aR[s][1].y);
        p[6] = f2bf(aR[s][1].z); p[7] = f2bf(aR[s][1].w);
        *(bf16x8*)(&Ab[b][tid * 8]) = p;   // phys slot tid = (row, kqp) linear
    };

    // ---- fragment read offsets (swizzled) ----
    int wr = w >> 2, wc = w & 3;
    int lrow = lane & 15, kqr = lane >> 4;
    int offA[4], offB[4];
    #pragma unroll
    for (int i = 0; i < 4; ++i) { int mr = wr * 64 + i * 16 + lrow; offA[i] = mr * 32 + (kqr ^ SWZ(mr)) * 8; }
    #pragma unroll
    for (int j = 0; j < 4; ++j) { int nr = wc * 64 + j * 16 + lrow; offB[j] = nr * 32 + (kqr ^ SWZ(nr)) * 8; }

    f32x4 acc[4][4];
    #pragma unroll
    for (int i = 0; i < 4; ++i)
        #pragma unroll
        for (int j = 0; j < 4; ++j) acc[i][j] = (f32x4){0.f, 0.f, 0.f, 0.f};

    auto comp = [&](int b) {
        bf16x8 af[4], bv[4];
        #pragma unroll
        for (int i = 0; i < 4; ++i) af[i] = *(const bf16x8*)&Ab[b][offA[i]];
        #pragma unroll
        for (int j = 0; j < 4; ++j) bv[j] = *(const bf16x8*)&Bb[b][offB[j]];
        __builtin_amdgcn_s_setprio(1);
        #pragma unroll
        for (int i = 0; i < 4; ++i)
            #pragma unroll
            for (int j = 0; j < 4; ++j)
                acc[i][j] = __builtin_amdgcn_mfma_f32_16x16x32_bf16(af[i], bv[j], acc[i][j], 0, 0, 0);
        __builtin_amdgcn_s_setprio(0);
    };

    // ---- prologue: fill bufs 0,1 ----
    if (LAYER == 1) {
        loadA1(0, 0); stageB(0, 0); loadA1(1, 1); stageB(1, 1);    // 8 vmem
        asm volatile("s_waitcnt vmcnt(4)" ::: "memory");           // A0,B0 done
        writeA1(0, 0);
        asm volatile("s_waitcnt lgkmcnt(0)" ::: "memory");
        __builtin_amdgcn_sched_barrier(0);
    } else {
        stageA2(0, 0); stageB(0, 0); stageA2(1, 1); stageB(1, 1);  // 6 vmem
        asm volatile("s_waitcnt vmcnt(3)" ::: "memory");           // A0,B0 done
    }
    __builtin_amdgcn_s_barrier();

    // ---- main loop: 16 K-steps of 32 ----
    #pragma unroll
    for (int t = 0; t < 16; ++t) {
        int cur = t % 3, wb = (t + 1) % 3, nx = (t + 2) % 3;
        if (t + 2 < 16) {
            if (LAYER == 1) loadA1(t + 2, t & 1);
            else            stageA2(t + 2, nx);
            stageB(t + 2, nx);
        }
        comp(cur);
        if (t == 15) break;
        if (LAYER == 1) {
            if (t + 2 < 16) asm volatile("s_waitcnt vmcnt(4)" ::: "memory");
            else            asm volatile("s_waitcnt vmcnt(0)" ::: "memory");
            writeA1((t + 1) & 1, wb);
            asm volatile("s_waitcnt lgkmcnt(0)" ::: "memory");
            __builtin_amdgcn_sched_barrier(0);
        } else {
            if (t + 2 < 16) asm volatile("s_waitcnt vmcnt(3)" ::: "memory");
            else            asm volatile("s_waitcnt vmcnt(0)" ::: "memory");
        }
        __builtin_amdgcn_s_barrier();
    }

    // ---- epilogue ----
    const float* be = bias + (size_t)e * 512;
    int colb = nb + wc * 64 + lrow;
    float bv[4];
    #pragma unroll
    for (int j = 0; j < 4; ++j) bv[j] = be[colb + j * 16];

    #pragma unroll
    for (int i = 0; i < 4; ++i) {
        #pragma unroll
        for (int q = 0; q < 4; ++q) {
            int rr = wr * 64 + i * 16 + ((lane >> 4) << 2) + q;
            if (m0 + rr < cnt) {
                if (LAYER == 1) {
                    short* hp = hOut + (size_t)(beg + m0 + rr) * HID + colb;
                    #pragma unroll
                    for (int j = 0; j < 4; ++j) {
                        float v = acc[i][j][q] + bv[j];
                        hp[j * 16] = f2bf(v > 0.f ? v : 0.f);
                    }
                } else {
                    float* op = out + (size_t)toks[rr] * HID + colb;
                    #pragma unroll
                    for (int j = 0; j < 4; ++j)
                        op[j * 16] = acc[i][j][q] + bv[j];
                }
            }
        }
    }
}

extern "C" void kernel_launch(void* const* d_in, const int* in_sizes, int n_in,
                              void* d_out, int out_size, void* d_ws, size_t ws_size,
                              hipStream_t stream)
{
    const float* x  = (const float*)d_in[0];
    const float* Wr = (const float*)d_in[1];
    const float* br = (const float*)d_in[2];
    const float* W1 = (const float*)d_in[3];
    const float* b1 = (const float*)d_in[4];
    const float* W2 = (const float*)d_in[5];
    const float* b2 = (const float*)d_in[6];

    float* out     = (float*)d_out;
    float* ids_out = out + (size_t)N_TOK * HID;

    char* ws     = (char*)d_ws;
    int* counts  = (int*)ws;            // 16 ints
    int* offsets = counts + 16;         // 11 used
    int* toff    = counts + 32;         // 11 used
    int* cursors = counts + 48;         // 16
    int* eid     = (int*)(ws + 1024);
    int* perm    = eid + N_TOK;
    short* W1bT  = (short*)(ws + 1024 + (size_t)2 * N_TOK * 4);
    short* W2bT  = W1bT + (size_t)NEXP * 512 * 512;
    short* h     = W2bT + (size_t)NEXP * 512 * 512;

    hipMemsetAsync(d_ws, 0, 1024, stream);
    router_kernel<<<2048, 256, 0, stream>>>(x, Wr, br, eid, ids_out, counts);
    wconvert_kernel<<<dim3(8, 8, 2 * NEXP), 256, 0, stream>>>(W1, W2, W1bT, W2bT);
    offsets_kernel<<<1, 64, 0, stream>>>(counts, offsets, toff);
    scatter_kernel<<<512, 256, 0, stream>>>(eid, offsets, cursors, perm);

    int ntiles = (N_TOK + 127) / 128 + NEXP;   // upper bound on row-tiles
    expert_gemm<1><<<dim3(ntiles, 2), 512, 0, stream>>>(x, nullptr, W1bT, b1, offsets, toff, perm, h, nullptr);
    expert_gemm<2><<<dim3(ntiles, 2), 512, 0, stream>>>(nullptr, h, W2bT, b2, offsets, toff, perm, nullptr, out);
}

// Round 5
// 367.044 us; speedup vs baseline: 1.4215x; 1.4215x over previous
//
#include <hip/hip_runtime.h>
#include <hip/hip_bf16.h>

#define N_TOK 131072
#define DIM   512
#define HID   512
#define NEXP  10

using bf16x8 = __attribute__((ext_vector_type(8))) short;
using f32x4  = __attribute__((ext_vector_type(4))) float;

__device__ __forceinline__ short f2bf(float f) {
    union { float f; unsigned u; } v; v.f = f;
    unsigned u = v.u;
    return (short)((u + 0x7FFFu + ((u >> 16) & 1u)) >> 16);   // RNE
}

#define GLOAD16(g, l) __builtin_amdgcn_global_load_lds( \
    (const __attribute__((address_space(1))) void*)(g),  \
    (__attribute__((address_space(3))) void*)(l), 16, 0, 0)

// ---------------- router: logits = x @ Wr^T + br, argmax; also emits xb = bf16(x) ----------------
__global__ __launch_bounds__(256) void router_kernel(
    const float* __restrict__ x, const float* __restrict__ Wr,
    const float* __restrict__ br, int* __restrict__ eid,
    float* __restrict__ ids_out, int* __restrict__ counts,
    short* __restrict__ xb)
{
    __shared__ float wr[NEXP][DIM];
    __shared__ int lcnt[NEXP];
    int tid = threadIdx.x;
    for (int i = tid; i < NEXP * DIM / 4; i += 256)
        ((float4*)wr)[i] = ((const float4*)Wr)[i];
    if (tid < NEXP) lcnt[tid] = 0;
    __syncthreads();

    int lane  = tid & 63;
    int wave  = tid >> 6;
    int gwave = blockIdx.x * 4 + wave;
    int nwav  = gridDim.x * 4;

    for (int t = gwave; t < N_TOK; t += nwav) {
        const float4* xr = (const float4*)(x + (size_t)t * DIM);
        float4 v0 = xr[lane * 2], v1 = xr[lane * 2 + 1];
        float xf[8] = {v0.x, v0.y, v0.z, v0.w, v1.x, v1.y, v1.z, v1.w};
        // emit bf16 copy of x (coalesced 16B/lane)
        bf16x8 p;
        #pragma unroll
        for (int j = 0; j < 8; ++j) p[j] = f2bf(xf[j]);
        *(bf16x8*)(xb + (size_t)t * DIM + lane * 8) = p;

        float dot[NEXP];
        #pragma unroll
        for (int e = 0; e < NEXP; ++e) {
            const float* wv = &wr[e][lane * 8];
            float s = 0.f;
            #pragma unroll
            for (int j = 0; j < 8; ++j) s = fmaf(xf[j], wv[j], s);
            dot[e] = s;
        }
        #pragma unroll
        for (int off = 32; off > 0; off >>= 1) {
            #pragma unroll
            for (int e = 0; e < NEXP; ++e) dot[e] += __shfl_xor(dot[e], off, 64);
        }
        if (lane == 0) {
            int best = 0; float bv = dot[0] + br[0];
            #pragma unroll
            for (int e = 1; e < NEXP; ++e) {
                float v = dot[e] + br[e];
                if (v > bv) { bv = v; best = e; }
            }
            eid[t] = best;
            ids_out[t] = (float)best;
            atomicAdd(&lcnt[best], 1);
        }
    }
    __syncthreads();
    if (tid < NEXP) atomicAdd(&counts[tid], lcnt[tid]);
}

// ---------------- prefix sums: token offsets + tile offsets (128-row tiles) ----------------
__global__ void offsets_kernel(const int* __restrict__ counts,
                               int* __restrict__ offsets, int* __restrict__ toff)
{
    if (threadIdx.x == 0) {
        int acc = 0, ta = 0;
        for (int e = 0; e < NEXP; ++e) {
            offsets[e] = acc; toff[e] = ta;
            acc += counts[e]; ta += (counts[e] + 127) >> 7;
        }
        offsets[NEXP] = acc; toff[NEXP] = ta;
    }
}

// ---------------- bucket scatter: perm[offset[e] + pos] = token ----------------
__global__ __launch_bounds__(256) void scatter_kernel(
    const int* __restrict__ eid, const int* __restrict__ offsets,
    int* __restrict__ cursors, int* __restrict__ perm)
{
    __shared__ int lcnt[NEXP], lbase[NEXP];
    int tid = threadIdx.x;
    if (tid < NEXP) lcnt[tid] = 0;
    __syncthreads();
    int t = blockIdx.x * 256 + tid;
    int e = 0, lpos = 0;
    if (t < N_TOK) {
        e = eid[t];
        lpos = atomicAdd(&lcnt[e], 1);
    }
    __syncthreads();
    if (tid < NEXP) lbase[tid] = atomicAdd(&cursors[tid], lcnt[tid]);
    __syncthreads();
    if (t < N_TOK) perm[offsets[e] + lbase[e] + lpos] = t;
}

// ---- transpose-convert weights: [512 k][512 n] f32 -> k-blocked bf16 [16 t][512 n][32 k] ----
__global__ __launch_bounds__(256) void wconvert_kernel(
    const float* __restrict__ W1, const float* __restrict__ W2,
    short* __restrict__ W1b, short* __restrict__ W2b)
{
    int mat = blockIdx.z;
    const float* src = (mat < NEXP) ? W1 + (size_t)mat * 512 * 512
                                    : W2 + (size_t)(mat - NEXP) * 512 * 512;
    short* dst = (mat < NEXP) ? W1b + (size_t)mat * 512 * 512
                              : W2b + (size_t)(mat - NEXP) * 512 * 512;
    __shared__ float tile[64][65];
    int r0 = blockIdx.y * 64, c0 = blockIdx.x * 64;   // r0 = k base, c0 = n base
    int tid = threadIdx.x;
    int tr = tid >> 4, tc4 = (tid & 15) * 4;
    #pragma unroll
    for (int i = 0; i < 4; ++i) {
        float4 v = *(const float4*)(src + (size_t)(r0 + i * 16 + tr) * 512 + c0 + tc4);
        tile[i * 16 + tr][tc4 + 0] = v.x; tile[i * 16 + tr][tc4 + 1] = v.y;
        tile[i * 16 + tr][tc4 + 2] = v.z; tile[i * 16 + tr][tc4 + 3] = v.w;
    }
    __syncthreads();
    int s   = (r0 + tc4) >> 5;     // k-step
    int kin = (r0 + tc4) & 31;     // k within step (0..28)
    #pragma unroll
    for (int i = 0; i < 4; ++i) {
        int cc = i * 16 + tr;      // n within tile
        ushort4 o;
        o.x = (ushort)f2bf(tile[tc4 + 0][cc]); o.y = (ushort)f2bf(tile[tc4 + 1][cc]);
        o.z = (ushort)f2bf(tile[tc4 + 2][cc]); o.w = (ushort)f2bf(tile[tc4 + 3][cc]);
        *(ushort4*)(dst + (size_t)s * 16384 + (size_t)(c0 + cc) * 32 + kin) = o;
    }
}

// ---------------- MFMA expert GEMM: 128 x 256 tile, K=512, 8 waves ----------------
// Unified staging: A and B both via global_load_lds (bf16), 3-buffer, counted vmcnt.
// LAYER==1: A = gathered xb rows, out = relu(.+b1) -> h (bf16, packed by perm order)
// LAYER==2: A = packed h rows,    out = . + b2 -> out[tok] (f32, scattered)
template<int LAYER>
__global__ __launch_bounds__(512, 4) void expert_gemm(
    const short* __restrict__ xb, const short* __restrict__ hA,
    const short* __restrict__ WT, const float* __restrict__ bias,
    const int* __restrict__ offsets, const int* __restrict__ toff,
    const int* __restrict__ perm,
    short* __restrict__ hOut, float* __restrict__ out)
{
    int g = blockIdx.x;
    if (g >= toff[NEXP]) return;
    int e = 0;
    #pragma unroll
    for (int k = 1; k < NEXP; ++k) e += (g >= toff[k]);
    int beg = offsets[e], cnt = offsets[e + 1] - beg;
    int m0 = (g - toff[e]) * 128;
    int nb = blockIdx.y * 256;

    __shared__ int toks[128];
    __shared__ short Ab[3][128 * 32];   // 8 KB each, [row][32k] linear
    __shared__ short Bb[3][256 * 32];   // 16 KB each, [n][32k] linear

    int tid = threadIdx.x, lane = tid & 63, w = tid >> 6;
    if (tid < 128) toks[tid] = perm[beg + min(m0 + tid, cnt - 1)];
    __syncthreads();

    // staging addresses (k-blocked B: step t tile is 16 KB contiguous)
    int srow = w * 16 + (lane >> 2);   // 0..127
    int slot = lane & 3;               // 16B quarter of the 64B k-row
    const short* WTe  = WT + (size_t)e * 512 * 512;
    const short* bSrc = WTe + (size_t)(nb + srow) * 32 + slot * 8;   // + t*16384
    const short* aSrc;
    if (LAYER == 1) aSrc = xb + (size_t)toks[srow] * DIM + slot * 8;                  // + t*32
    else            aSrc = hA + (size_t)(beg + min(m0 + srow, cnt - 1)) * HID + slot * 8;

    auto stage = [&](int t, int b) {   // 3 wave-wide loads, all linear LDS dest
        GLOAD16(bSrc + t * 16384,        (char*)&Bb[b][0] + w * 1024);
        GLOAD16(bSrc + t * 16384 + 4096, (char*)&Bb[b][0] + 8192 + w * 1024);  // rows +128
        GLOAD16(aSrc + t * 32,           (char*)&Ab[b][0] + w * 1024);
    };

    f32x4 acc[4][4];
    #pragma unroll
    for (int i = 0; i < 4; ++i)
        #pragma unroll
        for (int j = 0; j < 4; ++j) acc[i][j] = (f32x4){0.f, 0.f, 0.f, 0.f};

    int wr = w >> 2, wc = w & 3;       // 2 x 4 wave grid, 64x64 per wave
    int lrow = lane & 15;
    int lk   = (lane >> 4) * 8;

    auto comp = [&](int b) {
        const short* A = &Ab[b][0];
        const short* B = &Bb[b][0];
        bf16x8 af[4], bv[4];
        #pragma unroll
        for (int i = 0; i < 4; ++i)
            af[i] = *(const bf16x8*)(A + (wr * 64 + i * 16 + lrow) * 32 + lk);
        #pragma unroll
        for (int j = 0; j < 4; ++j)
            bv[j] = *(const bf16x8*)(B + (wc * 64 + j * 16 + lrow) * 32 + lk);
        __builtin_amdgcn_s_setprio(1);
        #pragma unroll
        for (int i = 0; i < 4; ++i)
            #pragma unroll
            for (int j = 0; j < 4; ++j)
                acc[i][j] = __builtin_amdgcn_mfma_f32_16x16x32_bf16(af[i], bv[j], acc[i][j], 0, 0, 0);
        __builtin_amdgcn_s_setprio(0);
    };

    // prologue: fill bufs 0,1 (3 loads each)
    stage(0, 0);
    stage(1, 1);
    asm volatile("s_waitcnt vmcnt(3)" ::: "memory");   // stage(0) complete
    __builtin_amdgcn_s_barrier();

    #pragma unroll
    for (int t = 0; t < 16; ++t) {
        if (t + 2 < 16) stage(t + 2, (t + 2) % 3);
        comp(t % 3);
        if (t == 15) break;
        if (t + 2 < 16) asm volatile("s_waitcnt vmcnt(3)" ::: "memory");  // t+1 complete
        else            asm volatile("s_waitcnt vmcnt(0)" ::: "memory");
        __builtin_amdgcn_s_barrier();
    }

    // ---- epilogue ----
    const float* be = bias + (size_t)e * 512;
    int colb = nb + wc * 64 + lrow;
    float bv[4];
    #pragma unroll
    for (int j = 0; j < 4; ++j) bv[j] = be[colb + j * 16];

    #pragma unroll
    for (int i = 0; i < 4; ++i) {
        #pragma unroll
        for (int q = 0; q < 4; ++q) {
            int rr = wr * 64 + i * 16 + ((lane >> 4) << 2) + q;
            if (m0 + rr < cnt) {
                if (LAYER == 1) {
                    short* hp = hOut + (size_t)(beg + m0 + rr) * HID + colb;
                    #pragma unroll
                    for (int j = 0; j < 4; ++j) {
                        float v = acc[i][j][q] + bv[j];
                        hp[j * 16] = f2bf(v > 0.f ? v : 0.f);
                    }
                } else {
                    float* op = out + (size_t)toks[rr] * HID + colb;
                    #pragma unroll
                    for (int j = 0; j < 4; ++j)
                        op[j * 16] = acc[i][j][q] + bv[j];
                }
            }
        }
    }
}

extern "C" void kernel_launch(void* const* d_in, const int* in_sizes, int n_in,
                              void* d_out, int out_size, void* d_ws, size_t ws_size,
                              hipStream_t stream)
{
    const float* x  = (const float*)d_in[0];
    const float* Wr = (const float*)d_in[1];
    const float* br = (const float*)d_in[2];
    const float* W1 = (const float*)d_in[3];
    const float* b1 = (const float*)d_in[4];
    const float* W2 = (const float*)d_in[5];
    const float* b2 = (const float*)d_in[6];

    float* out     = (float*)d_out;
    float* ids_out = out + (size_t)N_TOK * HID;

    char* ws     = (char*)d_ws;
    int* counts  = (int*)ws;            // 16 ints
    int* offsets = counts + 16;         // 11 used
    int* toff    = counts + 32;         // 11 used
    int* cursors = counts + 48;         // 16
    int* eid     = (int*)(ws + 1024);
    int* perm    = eid + N_TOK;
    short* W1b   = (short*)(ws + 1024 + (size_t)2 * N_TOK * 4);
    short* W2b   = W1b + (size_t)NEXP * 512 * 512;
    short* h     = W2b + (size_t)NEXP * 512 * 512;
    short* xb    = h   + (size_t)N_TOK * HID;

    hipMemsetAsync(d_ws, 0, 1024, stream);
    router_kernel<<<2048, 256, 0, stream>>>(x, Wr, br, eid, ids_out, counts, xb);
    wconvert_kernel<<<dim3(8, 8, 2 * NEXP), 256, 0, stream>>>(W1, W2, W1b, W2b);
    offsets_kernel<<<1, 64, 0, stream>>>(counts, offsets, toff);
    scatter_kernel<<<512, 256, 0, stream>>>(eid, offsets, cursors, perm);

    int ntiles = (N_TOK + 127) / 128 + NEXP;   // upper bound on row-tiles
    expert_gemm<1><<<dim3(ntiles, 2), 512, 0, stream>>>(xb, nullptr, W1b, b1, offsets, toff, perm, h, nullptr);
    expert_gemm<2><<<dim3(ntiles, 2), 512, 0, stream>>>(nullptr, h, W2b, b2, offsets, toff, perm, nullptr, out);
}